// Round 6
// baseline (289.309 us; speedup 1.0000x reference)
//
#include <hip/hip_runtime.h>

#define NBINS 10
#define ROWW  22         // dwords per thread-private LDS row: 10 x (u64 bin) + 2 pad
                         // odd*11 stride: bank-pair = (11*lane + b) % 16 bijective per
                         // 16 lanes => conflict-free b64 (the r0/r7 layout)
#define PART_STRIDE 32   // per-block partial row stride (padded from 30)

// Round 9: r8 base (private-row fire-and-forget ds_add_u64, no lgkmcnt in
// loop) + ONE change: CONTIGUOUS BLOCK TILING instead of grid-stride.
// Evidence: r8 equilibrium arithmetic shows capacity-bound memory at
// ~2.7 TB/s (wave stall 12.6k cyc == Little's-law queue latency; r6 proved
// more outstanding bytes don't raise BW). The scattered pattern (1 KB
// chunks 8 MB apart, alternating two streams 256 MB apart) is the last
// unexplored variable. Here block b owns a contiguous [start,end) quad
// range (balanced split, <=19 quads/thread so the packed fields stay
// exact); waves stream sequential 1 KB lines -> maximal DRAM row / L3
// line locality. Inner loop, LDS layout, epilogue: identical to r8.
__device__ __forceinline__ void process4(const float4& o, const float4& l,
                                         unsigned int* __restrict__ row)
{
    const float low0 = -1e-6f;
    const float step = (1.0f - low0) / 10.0f;   // fp32 linspace delta (const-folded)
    float xs[4] = {o.x, o.y, o.z, o.w};
    float ys[4] = {l.x, l.y, l.z, l.w};
#pragma unroll
    for (int k = 0; k < 4; ++k) {
        float x = xs[k];
        bool valid = (x > low0) & (x <= 1.0f);
        int e = (int)(x * 10.0f);
        e = e < 0 ? 0 : (e > 9 ? 9 : e);
        float fe  = (float)e;
        float hb0 = fmaf(fe,        step, low0);   // high[e-1]
        float hb1 = fmaf(fe + 1.0f, step, low0);   // high[e]
        int b = e + ((x > hb1) ? 1 : 0) - (((e > 0) & (x <= hb0)) ? 1 : 0);
        b = b < 0 ? 0 : (b > 9 ? 9 : b);
        float px = valid ? x : 0.0f;
        unsigned int lo = (unsigned int)fmaf(px, 1048576.0f, 0.5f); // fixed20, rn
        unsigned int hi = valid ? ((ys[k] > 0.5f) ? 0x10001u : 0x10000u) : 0u;
        unsigned long long inc = ((unsigned long long)hi << 32) | (unsigned long long)lo;
        // fire-and-forget: result unused -> ds_add_u64 (no rtn), no wait
        __hip_atomic_fetch_add((unsigned long long*)&row[2 * b], inc,
                               __ATOMIC_RELAXED, __HIP_MEMORY_SCOPE_WORKGROUP);
    }
}

__global__ __launch_bounds__(256) void calib_hist(
    const float* __restrict__ outputs,
    const float* __restrict__ labels,
    float* __restrict__ partials,
    long n)
{
    __shared__ __align__(16) unsigned int s_hist[256 * ROWW];   // 22528 B -> 7 blocks/CU

    const int tid = threadIdx.x;
    for (int j = tid; j < 256 * ROWW; j += 256) s_hist[j] = 0u;
    __syncthreads();

    unsigned int* __restrict__ row = &s_hist[tid * ROWW];

    const long total4 = n >> 2;
    const float4* o4 = (const float4*)outputs;
    const float4* l4 = (const float4*)labels;

    // balanced contiguous split: block b owns [bstart, bend) quads
    const long nb = (long)gridDim.x;
    const long bq = total4 / nb;
    const long br = total4 % nb;
    const long bid = (long)blockIdx.x;
    const long bstart = bid * bq + (bid < br ? bid : br);
    const long bend   = bstart + bq + (bid < br ? 1 : 0);

    long i = bstart + tid;
    if (i < bend) {
        float4 o = o4[i];
        float4 l = l4[i];
        for (;;) {
            const long ni = i + 256;                // contiguous: next 1KB line
            const bool hn = (ni < bend);
            float4 no, nl;
            if (hn) { no = o4[ni]; nl = l4[ni]; }   // loads in flight over process4
            process4(o, l, row);
            if (!hn) break;
            o = no; l = nl; i = ni;
        }
    }

    // scalar tail for n % 4 != 0 (not hit for this shape)
    const float low0 = -1e-6f;
    const float step = (1.0f - low0) / 10.0f;
    const long tail0 = total4 << 2;
    const long gid = bid * 256 + tid;
    const long gsz = nb * 256;
    for (long t = tail0 + gid; t < n; t += gsz) {
        float x = outputs[t];
        float y = labels [t];
        bool valid = (x > low0) & (x <= 1.0f);
        int e = (int)(x * 10.0f);
        e = e < 0 ? 0 : (e > 9 ? 9 : e);
        float fe  = (float)e;
        float hb0 = fmaf(fe,        step, low0);
        float hb1 = fmaf(fe + 1.0f, step, low0);
        int b = e + ((x > hb1) ? 1 : 0) - (((e > 0) & (x <= hb0)) ? 1 : 0);
        b = b < 0 ? 0 : (b > 9 ? 9 : b);
        float px = valid ? x : 0.0f;
        unsigned int lo = (unsigned int)fmaf(px, 1048576.0f, 0.5f);
        unsigned int hi = valid ? ((y > 0.5f) ? 0x10001u : 0x10000u) : 0u;
        unsigned long long inc = ((unsigned long long)hi << 32) | (unsigned long long)lo;
        __hip_atomic_fetch_add((unsigned long long*)&row[2 * b], inc,
                               __ATOMIC_RELAXED, __HIP_MEMORY_SCOPE_WORKGROUP);
    }

    __syncthreads();   // drains lgkmcnt: all atomics complete & visible

    // Block reduce (r8 structure): 240 threads, slot = tid%30
    // (0-9 prob, 10-19 tp, 20-29 count), chunk = tid/30 sums 32 rows;
    // partial stashed in the row pad word (offset 20) of row (chunk*30+slot).
    if (tid < 240) {
        int slot  = tid % 30;
        int chunk = tid / 30;
        int b = slot % NBINS;
        float acc = 0.0f;
        int r0 = chunk * 32;
        for (int r = r0; r < r0 + 32; ++r) {
            unsigned int base = (unsigned int)r * ROWW + 2 * b;
            if (slot < NBINS) {
                acc += (float)s_hist[base];                    // prob fixed20 (lo32)
            } else {
                unsigned int c = s_hist[base + 1];             // [cnt:16|tp:16]
                acc += (slot < 2 * NBINS) ? (float)(c & 0xFFFFu)  // tp
                                          : (float)(c >> 16);     // count
            }
        }
        if (slot < NBINS) acc *= (1.0f / 1048576.0f);          // back to prob units
        ((float*)s_hist)[(unsigned int)(chunk * 30 + slot) * ROWW + 20] = acc;
    }
    __syncthreads();
    if (tid < 3 * NBINS) {
        float s = 0.0f;
#pragma unroll
        for (int c = 0; c < 8; ++c)
            s += ((float*)s_hist)[(unsigned int)(c * 30 + tid) * ROWW + 20];
        partials[(long)blockIdx.x * PART_STRIDE + tid] = s;
    }
}

// Kernel 2: one block per output slot; double-precision accumulate of partials.
__global__ __launch_bounds__(256) void calib_reduce(
    const float* __restrict__ partials, float* __restrict__ out, int nrows)
{
    const int s   = blockIdx.x;    // 0..29
    const int tid = threadIdx.x;
    double acc = 0.0;
    for (int r = tid; r < nrows; r += 256)
        acc += (double)partials[(long)r * PART_STRIDE + s];
#pragma unroll
    for (int off = 32; off > 0; off >>= 1)
        acc += __shfl_down(acc, off, 64);
    __shared__ double wsum[4];
    if ((tid & 63) == 0) wsum[tid >> 6] = acc;
    __syncthreads();
    if (tid == 0) out[s] = (float)(wsum[0] + wsum[1] + wsum[2] + wsum[3]);
}

extern "C" void kernel_launch(void* const* d_in, const int* in_sizes, int n_in,
                              void* d_out, int out_size, void* d_ws, size_t ws_size,
                              hipStream_t stream) {
    const float* outputs = (const float*)d_in[0];
    const float* labels  = (const float*)d_in[1];
    float* out = (float*)d_out;
    long n = (long)in_sizes[0];

    // 22528 B LDS/block -> 7 blocks/CU; grid = 7*256 so all blocks co-resident;
    // balanced split => <=19 quads (76 elems) per thread: packed fields exact.
    int nblocks = 1792;
    size_t need = (size_t)nblocks * PART_STRIDE * sizeof(float);
    if (ws_size < need) {
        nblocks = (int)(ws_size / (PART_STRIDE * sizeof(float)));
        if (nblocks < 1) nblocks = 1;
    }
    float* partials = (float*)d_ws;

    calib_hist  <<<nblocks, 256, 0, stream>>>(outputs, labels, partials, n);
    calib_reduce<<<3 * NBINS, 256, 0, stream>>>(partials, out, nblocks);
}

// Round 8
// 258.081 us; speedup vs baseline: 1.1210x; 1.1210x over previous
//
#include <hip/hip_runtime.h>

#define NBINS 10
#define ROWW  22         // dwords per thread-private LDS row: 10 x (u64 bin) + 2 pad
                         // odd*11 stride: bank-pair = (11*lane + b) % 16 bijective per
                         // 16 lanes => conflict-free b64 (the r0/r7 layout)
#define PART_STRIDE 32   // per-block partial row stride (padded from 30)

typedef float vf4 __attribute__((ext_vector_type(4)));   // native vector: the
// __builtin_nontemporal_load builtin accepts this (HIP_vector_type it does not)

// Round 11: r8 base (grid-stride + private-row fire-and-forget ds_add_u64,
// 100us) + ONE change: NON-TEMPORAL input loads (r10 retry, compile fixed).
// Evidence: every variant lands at dur = 134MB / HBM_BW with FETCH_SIZE
// pinned at exactly half the 268MB read demand (inputs half-resident in the
// 256MB L3 across iterations) and HBM BW pinned at 1.2-1.35 TB/s (17% of
// the 6.3 TB/s copy ceiling) regardless of concurrency (r3/r6), access
// pattern (r9 contiguous: worse), or accumulator structure (r4/r7/r8 flat).
// nt loads (no-allocate / evict-first) stop the inputs from half-occupying
// L3, so the DRAM miss stream becomes dense sequential bursts.
__device__ __forceinline__ void process4(const vf4& o, const vf4& l,
                                         unsigned int* __restrict__ row)
{
    const float low0 = -1e-6f;
    const float step = (1.0f - low0) / 10.0f;   // fp32 linspace delta (const-folded)
    float xs[4] = {o.x, o.y, o.z, o.w};
    float ys[4] = {l.x, l.y, l.z, l.w};
#pragma unroll
    for (int k = 0; k < 4; ++k) {
        float x = xs[k];
        bool valid = (x > low0) & (x <= 1.0f);
        int e = (int)(x * 10.0f);
        e = e < 0 ? 0 : (e > 9 ? 9 : e);
        float fe  = (float)e;
        float hb0 = fmaf(fe,        step, low0);   // high[e-1]
        float hb1 = fmaf(fe + 1.0f, step, low0);   // high[e]
        int b = e + ((x > hb1) ? 1 : 0) - (((e > 0) & (x <= hb0)) ? 1 : 0);
        b = b < 0 ? 0 : (b > 9 ? 9 : b);
        float px = valid ? x : 0.0f;
        unsigned int lo = (unsigned int)fmaf(px, 1048576.0f, 0.5f); // fixed20, rn
        unsigned int hi = valid ? ((ys[k] > 0.5f) ? 0x10001u : 0x10000u) : 0u;
        unsigned long long inc = ((unsigned long long)hi << 32) | (unsigned long long)lo;
        // fire-and-forget: result unused -> ds_add_u64 (no rtn), no wait
        __hip_atomic_fetch_add((unsigned long long*)&row[2 * b], inc,
                               __ATOMIC_RELAXED, __HIP_MEMORY_SCOPE_WORKGROUP);
    }
}

__global__ __launch_bounds__(256) void calib_hist(
    const float* __restrict__ outputs,
    const float* __restrict__ labels,
    float* __restrict__ partials,
    long n)
{
    __shared__ __align__(16) unsigned int s_hist[256 * ROWW];   // 22528 B -> 7 blocks/CU

    const int tid = threadIdx.x;
    for (int j = tid; j < 256 * ROWW; j += 256) s_hist[j] = 0u;
    __syncthreads();

    unsigned int* __restrict__ row = &s_hist[tid * ROWW];

    const long total4 = n >> 2;
    const vf4* o4 = (const vf4*)outputs;
    const vf4* l4 = (const vf4*)labels;
    const long gid = (long)blockIdx.x * blockDim.x + tid;
    const long gsz = (long)gridDim.x * blockDim.x;

    long i = gid;
    if (i < total4) {
        vf4 o = __builtin_nontemporal_load(&o4[i]);
        vf4 l = __builtin_nontemporal_load(&l4[i]);
        for (;;) {
            const long ni = i + gsz;
            const bool hn = (ni < total4);
            vf4 no, nl;
            if (hn) {                               // loads in flight over process4
                no = __builtin_nontemporal_load(&o4[ni]);
                nl = __builtin_nontemporal_load(&l4[ni]);
            }
            process4(o, l, row);
            if (!hn) break;
            o = no; l = nl; i = ni;
        }
    }

    // scalar tail for n % 4 != 0 (not hit for this shape)
    const float low0 = -1e-6f;
    const float step = (1.0f - low0) / 10.0f;
    const long tail0 = total4 << 2;
    for (long t = tail0 + gid; t < n; t += gsz) {
        float x = __builtin_nontemporal_load(&outputs[t]);
        float y = __builtin_nontemporal_load(&labels [t]);
        bool valid = (x > low0) & (x <= 1.0f);
        int e = (int)(x * 10.0f);
        e = e < 0 ? 0 : (e > 9 ? 9 : e);
        float fe  = (float)e;
        float hb0 = fmaf(fe,        step, low0);
        float hb1 = fmaf(fe + 1.0f, step, low0);
        int b = e + ((x > hb1) ? 1 : 0) - (((e > 0) & (x <= hb0)) ? 1 : 0);
        b = b < 0 ? 0 : (b > 9 ? 9 : b);
        float px = valid ? x : 0.0f;
        unsigned int lo = (unsigned int)fmaf(px, 1048576.0f, 0.5f);
        unsigned int hi = valid ? ((y > 0.5f) ? 0x10001u : 0x10000u) : 0u;
        unsigned long long inc = ((unsigned long long)hi << 32) | (unsigned long long)lo;
        __hip_atomic_fetch_add((unsigned long long*)&row[2 * b], inc,
                               __ATOMIC_RELAXED, __HIP_MEMORY_SCOPE_WORKGROUP);
    }

    __syncthreads();   // drains lgkmcnt: all atomics complete & visible

    // Block reduce (r8 structure): 240 threads, slot = tid%30
    // (0-9 prob, 10-19 tp, 20-29 count), chunk = tid/30 sums 32 rows;
    // partial stashed in the row pad word (offset 20) of row (chunk*30+slot).
    if (tid < 240) {
        int slot  = tid % 30;
        int chunk = tid / 30;
        int b = slot % NBINS;
        float acc = 0.0f;
        int r0 = chunk * 32;
        for (int r = r0; r < r0 + 32; ++r) {
            unsigned int base = (unsigned int)r * ROWW + 2 * b;
            if (slot < NBINS) {
                acc += (float)s_hist[base];                    // prob fixed20 (lo32)
            } else {
                unsigned int c = s_hist[base + 1];             // [cnt:16|tp:16]
                acc += (slot < 2 * NBINS) ? (float)(c & 0xFFFFu)  // tp
                                          : (float)(c >> 16);     // count
            }
        }
        if (slot < NBINS) acc *= (1.0f / 1048576.0f);          // back to prob units
        ((float*)s_hist)[(unsigned int)(chunk * 30 + slot) * ROWW + 20] = acc;
    }
    __syncthreads();
    if (tid < 3 * NBINS) {
        float s = 0.0f;
#pragma unroll
        for (int c = 0; c < 8; ++c)
            s += ((float*)s_hist)[(unsigned int)(c * 30 + tid) * ROWW + 20];
        partials[(long)blockIdx.x * PART_STRIDE + tid] = s;
    }
}

// Kernel 2: one block per output slot; double-precision accumulate of partials.
__global__ __launch_bounds__(256) void calib_reduce(
    const float* __restrict__ partials, float* __restrict__ out, int nrows)
{
    const int s   = blockIdx.x;    // 0..29
    const int tid = threadIdx.x;
    double acc = 0.0;
    for (int r = tid; r < nrows; r += 256)
        acc += (double)partials[(long)r * PART_STRIDE + s];
#pragma unroll
    for (int off = 32; off > 0; off >>= 1)
        acc += __shfl_down(acc, off, 64);
    __shared__ double wsum[4];
    if ((tid & 63) == 0) wsum[tid >> 6] = acc;
    __syncthreads();
    if (tid == 0) out[s] = (float)(wsum[0] + wsum[1] + wsum[2] + wsum[3]);
}

extern "C" void kernel_launch(void* const* d_in, const int* in_sizes, int n_in,
                              void* d_out, int out_size, void* d_ws, size_t ws_size,
                              hipStream_t stream) {
    const float* outputs = (const float*)d_in[0];
    const float* labels  = (const float*)d_in[1];
    float* out = (float*)d_out;
    long n = (long)in_sizes[0];

    // 22528 B LDS/block -> 7 blocks/CU; grid = 7*256 so all blocks co-resident;
    // <=76 elems/thread keeps all packed fields exact.
    int nblocks = 1792;
    size_t need = (size_t)nblocks * PART_STRIDE * sizeof(float);
    if (ws_size < need) {
        nblocks = (int)(ws_size / (PART_STRIDE * sizeof(float)));
        if (nblocks < 1) nblocks = 1;
    }
    float* partials = (float*)d_ws;

    calib_hist  <<<nblocks, 256, 0, stream>>>(outputs, labels, partials, n);
    calib_reduce<<<3 * NBINS, 256, 0, stream>>>(partials, out, nblocks);
}